// Round 1
// 75.860 us; speedup vs baseline: 1.0075x; 1.0075x over previous
//
#include <hip/hip_runtime.h>

#define BATCH 262144

struct C { float r, i; };

// General rotation on one column entry pair: u' = ep*ct*u - st*v ; v' = ep*st*u + ct*v
__device__ __forceinline__ void rotp(C& u, C& v, float ct, float st, float cp, float sp) {
    float ar = cp * ct, ai = sp * ct;   // ep*ct
    float br = cp * st, bi = sp * st;   // ep*st
    C nu, nv;
    nu.r = ar * u.r - ai * u.i - st * v.r;
    nu.i = ar * u.i + ai * u.r - st * v.i;
    nv.r = br * u.r - bi * u.i + ct * v.r;
    nv.i = br * u.i + bi * u.r + ct * v.i;
    u = nu; v = nv;
}

// phi == 0: pure real Givens rotation
__device__ __forceinline__ void rotr(C& u, C& v, float ct, float st) {
    C nu, nv;
    nu.r = ct * u.r - st * v.r;
    nu.i = ct * u.i - st * v.i;
    nv.r = st * u.r + ct * v.r;
    nv.i = st * u.i + ct * v.i;
    u = nu; v = nv;
}

// Batch-uniform trig, computed once per thread, reused for both elements.
struct UT {
    float ct0, st0, ct1, st1, ct2, st2, ct3, st3;   // pth[0..3], phi=0
    float ct4, st4, cp0, sp0;                       // k=7  (pth[4], pphi[0])
    float ct5, st5, cp1, sp1;                       // k=8  (pth[5], pphi[1])
    float ct6, st6, cp2, sp2;                       // k=12 (pth[6], pphi[2])
    float ct7, st7, cp3, sp3;                       // k=13 (pth[7], pphi[3])
};

#define ROTRU(I, J, CT, ST) do { rotr(a##I, a##J, CT, ST); rotr(b##I, b##J, CT, ST); } while (0)
#define ROTPU(I, J, CT, ST, CP, SP) do { rotp(a##I, a##J, CT, ST, CP, SP); rotp(b##I, b##J, CT, ST, CP, SP); } while (0)
#define ROTPD(I, J, TH, PH) do { \
        float st_ = __sinf(TH), ct_ = __cosf(TH); \
        float sp_ = __sinf(PH), cp_ = __cosf(PH); \
        rotp(a##I, a##J, ct_, st_, cp_, sp_); \
        rotp(b##I, b##J, ct_, st_, cp_, sp_); \
    } while (0)

__device__ __forceinline__ void compute_elem(
    float xs0, float xs1, float xs2, float xs3, float xs4, float xs5,
    float xs6, float xs7, float xs8, float xs9, float xs10, float xs11,
    const UT& u, float* __restrict__ row)
{
    // Only columns 0 and 3 of U are read downstream: track two complex 6-vectors.
    C a0{1.f,0.f}, a1{0.f,0.f}, a2{0.f,0.f}, a3{0.f,0.f}, a4{0.f,0.f}, a5{0.f,0.f};
    C b0{0.f,0.f}, b1{0.f,0.f}, b2{0.f,0.f}, b3{1.f,0.f}, b4{0.f,0.f}, b5{0.f,0.f};

    ROTRU(0, 1, u.ct0, u.st0);                 // k=0
    ROTRU(4, 5, u.ct1, u.st1);                 // k=1
    ROTRU(1, 2, u.ct2, u.st2);                 // k=2
    ROTRU(3, 4, u.ct3, u.st3);                 // k=3
    ROTPD(0, 1, xs3,  xs0);                    // k=4
    ROTPD(2, 3, xs4,  xs1);                    // k=5
    ROTPD(4, 5, xs5,  xs2);                    // k=6
    ROTPU(1, 2, u.ct4, u.st4, u.cp0, u.sp0);   // k=7
    ROTPU(3, 4, u.ct5, u.st5, u.cp1, u.sp1);   // k=8
    ROTPD(0, 1, xs9,  xs6);                    // k=9
    ROTPD(2, 3, xs10, xs7);                    // k=10
    ROTPD(4, 5, xs11, xs8);                    // k=11
    ROTPU(1, 2, u.ct6, u.st6, u.cp2, u.sp2);   // k=12
    ROTPU(3, 4, u.ct7, u.st7, u.cp3, u.sp3);   // k=13

#define PAIR(I, J, K) \
    { float re_ = a##I.r * b##J.r - a##I.i * b##J.i + a##J.r * b##I.r - a##J.i * b##I.i; \
      float im_ = a##I.r * b##J.i + a##I.i * b##J.r + a##J.r * b##I.i + a##J.i * b##I.r; \
      m##K = re_ * re_ + im_ * im_; s += m##K; }

    float m0,m1,m2,m3,m4,m5,m6,m7,m8,m9,m10,m11,m12,m13,m14;
    float s = 0.f;
    PAIR(0,1,0)  PAIR(0,2,1)  PAIR(0,3,2)  PAIR(0,4,3)  PAIR(0,5,4)
    PAIR(1,2,5)  PAIR(1,3,6)  PAIR(1,4,7)  PAIR(1,5,8)
    PAIR(2,3,9)  PAIR(2,4,10) PAIR(2,5,11)
    PAIR(3,4,12) PAIR(3,5,13)
    PAIR(4,5,14)
#undef PAIR

    // out_k = sqrt(m_k / max(s, eps^2)); tolerance is 2^-8 -> raw v_rcp/v_sqrt suffice
    float invs = __builtin_amdgcn_rcpf(fmaxf(s, 1e-24f));
    row[0]  = __builtin_amdgcn_sqrtf(m0  * invs);
    row[1]  = __builtin_amdgcn_sqrtf(m1  * invs);
    row[2]  = __builtin_amdgcn_sqrtf(m2  * invs);
    row[3]  = __builtin_amdgcn_sqrtf(m3  * invs);
    row[4]  = __builtin_amdgcn_sqrtf(m4  * invs);
    row[5]  = __builtin_amdgcn_sqrtf(m5  * invs);
    row[6]  = __builtin_amdgcn_sqrtf(m6  * invs);
    row[7]  = __builtin_amdgcn_sqrtf(m7  * invs);
    row[8]  = __builtin_amdgcn_sqrtf(m8  * invs);
    row[9]  = __builtin_amdgcn_sqrtf(m9  * invs);
    row[10] = __builtin_amdgcn_sqrtf(m10 * invs);
    row[11] = __builtin_amdgcn_sqrtf(m11 * invs);
    row[12] = __builtin_amdgcn_sqrtf(m12 * invs);
    row[13] = __builtin_amdgcn_sqrtf(m13 * invs);
    row[14] = __builtin_amdgcn_sqrtf(m14 * invs);
}

__global__ __launch_bounds__(256) void bqnn_kernel(
    const float* __restrict__ x,
    const float* __restrict__ pphi,
    const float* __restrict__ pth,
    const float* __restrict__ ink,
    const float* __restrict__ inb,
    float* __restrict__ out) {
    // 2 elements per thread: 512 elements per block
    __shared__ alignas(16) float ls[512 * 15];

    const int t = threadIdx.x;
    const long long e0 = (long long)blockIdx.x * 512 + t;   // second elem = e0 + 256

    // Issue all global loads up front (48 B per element, lines fully consumed per block)
    const float4* x4 = reinterpret_cast<const float4*>(x);
    float4 A0 = x4[e0 * 3 + 0], A1 = x4[e0 * 3 + 1], A2 = x4[e0 * 3 + 2];
    float4 B0 = x4[(e0 + 256) * 3 + 0], B1 = x4[(e0 + 256) * 3 + 1], B2 = x4[(e0 + 256) * 3 + 2];

    // Batch-uniform trig once per thread (s_load'd params; v_sin/v_cos)
    UT u;
    u.ct0 = __cosf(pth[0]); u.st0 = __sinf(pth[0]);
    u.ct1 = __cosf(pth[1]); u.st1 = __sinf(pth[1]);
    u.ct2 = __cosf(pth[2]); u.st2 = __sinf(pth[2]);
    u.ct3 = __cosf(pth[3]); u.st3 = __sinf(pth[3]);
    u.ct4 = __cosf(pth[4]); u.st4 = __sinf(pth[4]);
    u.ct5 = __cosf(pth[5]); u.st5 = __sinf(pth[5]);
    u.ct6 = __cosf(pth[6]); u.st6 = __sinf(pth[6]);
    u.ct7 = __cosf(pth[7]); u.st7 = __sinf(pth[7]);
    u.cp0 = __cosf(pphi[0]); u.sp0 = __sinf(pphi[0]);
    u.cp1 = __cosf(pphi[1]); u.sp1 = __sinf(pphi[1]);
    u.cp2 = __cosf(pphi[2]); u.sp2 = __sinf(pphi[2]);
    u.cp3 = __cosf(pphi[3]); u.sp3 = __sinf(pphi[3]);

    // Uniform scale/bias (CSE'd scalar loads)
    const float k0=ink[0], k1=ink[1], k2=ink[2], k3=ink[3], k4=ink[4],  k5=ink[5];
    const float k6=ink[6], k7=ink[7], k8=ink[8], k9=ink[9], k10=ink[10], k11=ink[11];
    const float c0=inb[0], c1=inb[1], c2=inb[2], c3=inb[3], c4=inb[4],  c5=inb[5];
    const float c6=inb[6], c7=inb[7], c8=inb[8], c9=inb[9], c10=inb[10], c11=inb[11];

    compute_elem(A0.x*k0+c0, A0.y*k1+c1, A0.z*k2+c2, A0.w*k3+c3,
                 A1.x*k4+c4, A1.y*k5+c5, A1.z*k6+c6, A1.w*k7+c7,
                 A2.x*k8+c8, A2.y*k9+c9, A2.z*k10+c10, A2.w*k11+c11,
                 u, ls + t * 15);
    compute_elem(B0.x*k0+c0, B0.y*k1+c1, B0.z*k2+c2, B0.w*k3+c3,
                 B1.x*k4+c4, B1.y*k5+c5, B1.z*k6+c6, B1.w*k7+c7,
                 B2.x*k8+c8, B2.y*k9+c9, B2.z*k10+c10, B2.w*k11+c11,
                 u, ls + (256 + t) * 15);

    __syncthreads();

    // Coalesced vectorized flush: 7680 contiguous floats = 1920 float4 per block
    float4* o4 = reinterpret_cast<float4*>(out) + (long long)blockIdx.x * 1920;
    const float4* l4 = reinterpret_cast<const float4*>(ls);
    #pragma unroll
    for (int i = 0; i < 7; ++i) {
        int idx = i * 256 + t;
        o4[idx] = l4[idx];
    }
    if (t < 128) {
        int idx = 1792 + t;
        o4[idx] = l4[idx];
    }
}

extern "C" void kernel_launch(void* const* d_in, const int* in_sizes, int n_in,
                              void* d_out, int out_size, void* d_ws, size_t ws_size,
                              hipStream_t stream) {
    const float* x    = (const float*)d_in[0];
    const float* pphi = (const float*)d_in[1];
    const float* pth  = (const float*)d_in[2];
    const float* ink  = (const float*)d_in[3];
    const float* inb  = (const float*)d_in[4];
    float* out = (float*)d_out;

    bqnn_kernel<<<BATCH / 512, 256, 0, stream>>>(x, pphi, pth, ink, inb, out);
}